// Round 11
// baseline (875.458 us; speedup 1.0000x reference)
//
#include <hip/hip_runtime.h>
#include <hip/hip_fp16.h>

typedef _Float16 f16;
typedef _Float16 f16x2 __attribute__((ext_vector_type(2)));
typedef _Float16 f16x8 __attribute__((ext_vector_type(8)));
typedef __fp16   hf2   __attribute__((ext_vector_type(2)));
typedef float    f32x2 __attribute__((ext_vector_type(2)));
typedef float    f32x4 __attribute__((ext_vector_type(4)));
typedef unsigned ui4   __attribute__((ext_vector_type(4)));

#define T_STEPS 2048
#define BATCH   16
#define DIM     1024

// ---------------------------------------------------------------------------
__device__ __forceinline__ void async16(void* lds, const void* g) {
  __builtin_amdgcn_global_load_lds(
      (const __attribute__((address_space(1))) void*)g,
      (__attribute__((address_space(3))) void*)lds, 16, 0, 0);
}

#define WAITV_(n) asm volatile("s_waitcnt vmcnt(" #n ")" ::: "memory")
#define WAITV(n) WAITV_(n)

__device__ __forceinline__ float fma_mix_lo(unsigned p, float one, float h) {
  float d;
  asm("v_fma_mix_f32 %0, %1, %2, %3 op_sel:[0,0,0] op_sel_hi:[1,0,0]"
      : "=v"(d) : "v"(p), "v"(one), "v"(h));
  return d;
}
__device__ __forceinline__ float fma_mix_hi(unsigned p, float one, float h) {
  float d;
  asm("v_fma_mix_f32 %0, %1, %2, %3 op_sel:[1,0,0] op_sel_hi:[1,0,0]"
      : "=v"(d) : "v"(p), "v"(one), "v"(h));
  return d;
}

__device__ __forceinline__ unsigned pk16(float a, float b) {
  hf2 r = __builtin_amdgcn_cvt_pkrtz(a, b);
  return __builtin_bit_cast(unsigned, r);
}

template <int CTRL>
__device__ __forceinline__ float dpp_add(float x) {
  int m = __builtin_amdgcn_update_dpp(0, __float_as_int(x), CTRL, 0xf, 0xf, true);
  return x + __int_as_float(m);
}

#define AQ(p) __hip_atomic_load((p), __ATOMIC_ACQUIRE, __HIP_MEMORY_SCOPE_WORKGROUP)
#define RL(p, v) __hip_atomic_store((p), (v), __ATOMIC_RELEASE, __HIP_MEMORY_SCOPE_WORKGROUP)

// ---------------------------------------------------------------------------
// f32 -> f16 convert, 8 elems/thread
__global__ void cvt_kernel(const float* __restrict__ src, f16* __restrict__ dst,
                           int n8) {
  int i = blockIdx.x * 256 + threadIdx.x;
  if (i >= n8) return;
  const float4* s4 = reinterpret_cast<const float4*>(src);
  float4 a = s4[2 * i], b = s4[2 * i + 1];
  f16x8 o;
  o[0] = (f16)a.x; o[1] = (f16)a.y; o[2] = (f16)a.z; o[3] = (f16)a.w;
  o[4] = (f16)b.x; o[5] = (f16)b.y; o[6] = (f16)b.z; o[7] = (f16)b.w;
  *reinterpret_cast<f16x8*>(dst + (size_t)i * 8) = o;
}

// ---------------------------------------------------------------------------
// Dual GEMM (R6 proven): P[m,e] = (x@W^T + b) * sigmoid(x@Wg^T + bg)
__global__ __launch_bounds__(256, 2)
void dual_gemm(const f16* __restrict__ xh, const f16* __restrict__ wh,
               const f16* __restrict__ wgh, const float* __restrict__ bias,
               const float* __restrict__ biasg, f16* __restrict__ P) {
  __shared__ f16 As[128 * 32];
  __shared__ f16 Bs[128 * 32];
  __shared__ f16 Gs[128 * 32];

  const int tid = threadIdx.x;
  const int bid = blockIdx.x;
  const int swz = ((bid & 7) << 8) | (bid >> 3);
  const int m0 = (swz >> 3) * 128;
  const int e0 = (swz & 7) * 128;

  const int lane = tid & 63;
  const int wave = tid >> 6;
  const int wrow = (wave >> 1) * 64;
  const int wcol = (wave & 1) * 64;
  const int fr = lane & 15;
  const int fc = lane >> 4;

  f32x4 acc1[4][4], acc2[4][4];
#pragma unroll
  for (int i = 0; i < 4; ++i)
#pragma unroll
    for (int j = 0; j < 4; ++j) {
      acc1[i][j] = {0.f, 0.f, 0.f, 0.f};
      acc2[i][j] = {0.f, 0.f, 0.f, 0.f};
    }

  const int    srow  = tid >> 2;
  const size_t sbyte = (size_t)(tid & 3) * 16;
  const char* ga = (const char*)xh  + ((size_t)(m0 + srow)) * 2048 + sbyte;
  const char* gb = (const char*)wh  + ((size_t)(e0 + srow)) * 2048 + sbyte;
  const char* gg = (const char*)wgh + ((size_t)(e0 + srow)) * 2048 + sbyte;
  char* la = (char*)&As[0] + (size_t)wave * 1024;
  char* lb = (char*)&Bs[0] + (size_t)wave * 1024;
  char* lg = (char*)&Gs[0] + (size_t)wave * 1024;

  for (int kk = 0; kk < 1024; kk += 32) {
    const size_t ko = (size_t)kk * 2;
    async16(la,        ga + ko);
    async16(la + 4096, ga + ko + (size_t)64 * 2048);
    async16(lb,        gb + ko);
    async16(lb + 4096, gb + ko + (size_t)64 * 2048);
    async16(lg,        gg + ko);
    async16(lg + 4096, gg + ko + (size_t)64 * 2048);
    asm volatile("s_waitcnt vmcnt(0)" ::: "memory");
    __syncthreads();

    f16x8 af[4], bf[4], gf[4];
#pragma unroll
    for (int i = 0; i < 4; ++i) {
      af[i] = *reinterpret_cast<const f16x8*>(&As[(wrow + i * 16 + fr) * 32 + fc * 8]);
      bf[i] = *reinterpret_cast<const f16x8*>(&Bs[(wcol + i * 16 + fr) * 32 + fc * 8]);
      gf[i] = *reinterpret_cast<const f16x8*>(&Gs[(wcol + i * 16 + fr) * 32 + fc * 8]);
    }
#pragma unroll
    for (int mi = 0; mi < 4; ++mi)
#pragma unroll
      for (int ni = 0; ni < 4; ++ni) {
        acc1[mi][ni] = __builtin_amdgcn_mfma_f32_16x16x32_f16(af[mi], bf[ni], acc1[mi][ni], 0, 0, 0);
        acc2[mi][ni] = __builtin_amdgcn_mfma_f32_16x16x32_f16(af[mi], gf[ni], acc2[mi][ni], 0, 0, 0);
      }
    __syncthreads();
  }

#pragma unroll
  for (int ni = 0; ni < 4; ++ni) {
    const int e = e0 + wcol + ni * 16 + fr;
    const float bb  = bias[e];
    const float bbg = biasg[e];
#pragma unroll
    for (int mi = 0; mi < 4; ++mi) {
      const int mrow = m0 + wrow + mi * 16 + fc * 4;
#pragma unroll
      for (int j = 0; j < 4; ++j) {
        float z1 = acc1[mi][ni][j] + bb;
        float z2 = acc2[mi][ni][j] + bbg;
        float s  = 1.0f / (1.0f + __expf(-z2));
        P[(size_t)(mrow + j) * DIM + e] = (f16)(z1 * s);
      }
    }
  }
}

// ---------------------------------------------------------------------------
// Producer-consumer scan, 4 waves/block, GROUP-SYNCHRONOUS (16 rows/group):
//  wave0: serial chain, LDS-only I/O (zero vmcnt waits on the chain).
//  wave1: loader, double-buffered 16-row groups via global_load_lds.
//  wave2/3: storers (row parity): hring(f16) -> hout row r+1 (f32) + fused
//           silu -> out row r. Replaces the separate silu kernel.
// Window trace (deadlock-free): loader publishes flags[0]=16 unconditionally
// after groups 0,1 issued + group0 landed; wave0 group0 -> flags[1]=16;
// loader g=2 polls flags[1]>=16, issues into buf0, publishes flags[0]=32; ...
// wave0 hring slot for row t overwrites row t-32; storers polled >=16(g-1)
// at group top cover rows <= t-16. 1-group slack on every edge.
__global__ __launch_bounds__(256, 1)
void scan_pc_kernel(const f16* __restrict__ P, const float* __restrict__ h0,
                    float* __restrict__ hout, float* __restrict__ out) {
  __shared__ f16 pring[32][1024];   // 64 KB: 2 groups x 16 P rows
  __shared__ f16 hring[32][1024];   // 64 KB: h rows (f16), slot = t & 31
  __shared__ unsigned flags[4];     // [0] rows landed, [1] steps done,
                                    // [2]/[3] storer progress (even/odd)

  const int b = blockIdx.x;
  const int lane = threadIdx.x & 63;
  const int wid = threadIdx.x >> 6;

  if (threadIdx.x == 0) { flags[0] = 0; flags[1] = 0; flags[2] = 0; flags[3] = 1; }
  __syncthreads();

  if (wid == 0) {
    // ----------------- compute wave: lane l owns elems 8l..8l+7, 512+8l.. --
    f32x4 h4[4];
    {
      const f32x4* s = (const f32x4*)(h0 + (size_t)b * DIM);
      f32x4* d = (f32x4*)(hout + (size_t)b * DIM);  // h row 0 = h0 (f32)
      h4[0] = s[2 * lane];       d[2 * lane]       = h4[0];
      h4[1] = s[2 * lane + 1];   d[2 * lane + 1]   = h4[1];
      h4[2] = s[128 + 2 * lane]; d[128 + 2 * lane] = h4[2];
      h4[3] = s[129 + 2 * lane]; d[129 + 2 * lane] = h4[3];
    }
    const float one = 1.0f;
    const char* prb = (const char*)&pring[0][0] + (size_t)lane * 16;
    char*       hwb = (char*)&hring[0][0] + (size_t)lane * 16;

#define PSTEP(CUR, NXT, U)                                                    \
  {                                                                           \
    if ((U) < 15) {                                                           \
      NXT[0] = *(const ui4*)(pg + ((U) + 1) * 2048);                          \
      NXT[1] = *(const ui4*)(pg + ((U) + 1) * 2048 + 1024);                   \
    }                                                                         \
    f32x4 v4[4];                                                              \
    _Pragma("unroll")                                                         \
    for (int c = 0; c < 4; ++c) {                                             \
      const unsigned w0 = CUR[c >> 1][(c & 1) * 2];                           \
      const unsigned w1 = CUR[c >> 1][(c & 1) * 2 + 1];                       \
      v4[c][0] = fma_mix_lo(w0, one, h4[c][0]);                               \
      v4[c][1] = fma_mix_hi(w0, one, h4[c][1]);                               \
      v4[c][2] = fma_mix_lo(w1, one, h4[c][2]);                               \
      v4[c][3] = fma_mix_hi(w1, one, h4[c][3]);                               \
    }                                                                         \
    f32x2 sE, sO;                                                             \
    {                                                                         \
      f32x2 e0v = __builtin_shufflevector(v4[0], v4[0], 0, 1);                \
      f32x2 o0v = __builtin_shufflevector(v4[0], v4[0], 2, 3);                \
      sE = e0v * e0v;                                                         \
      sO = o0v * o0v;                                                         \
      _Pragma("unroll")                                                       \
      for (int c = 1; c < 4; ++c) {                                           \
        f32x2 ec = __builtin_shufflevector(v4[c], v4[c], 0, 1);               \
        f32x2 oc = __builtin_shufflevector(v4[c], v4[c], 2, 3);               \
        sE += ec * ec;                                                        \
        sO += oc * oc;                                                        \
      }                                                                       \
    }                                                                         \
    f32x2 sC = sE + sO;                                                       \
    float ss = sC[0] + sC[1];                                                 \
    ss = dpp_add<0x111>(ss);                                                  \
    ss = dpp_add<0x112>(ss);                                                  \
    ss = dpp_add<0x114>(ss);                                                  \
    ss = dpp_add<0x118>(ss);                                                  \
    ss = dpp_add<0x142>(ss);                                                  \
    ss = dpp_add<0x143>(ss);                                                  \
    float tot = __int_as_float(__builtin_amdgcn_readlane(__float_as_int(ss), 63)); \
    float rs = __builtin_amdgcn_rsqf(fmaf(tot, 9.765625e-4f, 1e-6f));         \
    _Pragma("unroll")                                                         \
    for (int c = 0; c < 4; ++c) h4[c] = v4[c] * rs;                           \
    ui4 o0, o1;                                                               \
    o0[0] = pk16(h4[0][0], h4[0][1]); o0[1] = pk16(h4[0][2], h4[0][3]);       \
    o0[2] = pk16(h4[1][0], h4[1][1]); o0[3] = pk16(h4[1][2], h4[1][3]);       \
    o1[0] = pk16(h4[2][0], h4[2][1]); o1[1] = pk16(h4[2][2], h4[2][3]);       \
    o1[2] = pk16(h4[3][0], h4[3][1]); o1[3] = pk16(h4[3][2], h4[3][3]);       \
    *(ui4*)(hwg + (U) * 2048) = o0;                                           \
    *(ui4*)(hwg + (U) * 2048 + 1024) = o1;                                    \
    if ((U) == 7)  RL(&flags[1], (unsigned)(gbase + 8));                      \
    if ((U) == 15) RL(&flags[1], (unsigned)(gbase + 16));                     \
  }

#pragma unroll 1
    for (int g = 0; g < 128; ++g) {
      const unsigned need0 = (unsigned)((g + 1) * 16);
      { int gd = 1 << 22;
        while (gd-- && AQ(&flags[0]) < need0) __builtin_amdgcn_s_sleep(1); }
      if (g >= 2) {
        const unsigned needs = (unsigned)((g - 1) * 16);
        int gd = 1 << 22;
        while (gd-- && (AQ(&flags[2]) < needs || AQ(&flags[3]) < needs))
          __builtin_amdgcn_s_sleep(1);
      }
      const char* pg  = prb + (g & 1) * 32768;
      char*       hwg = hwb + (g & 1) * 32768;
      const int gbase = g * 16;
      ui4 pA[2], pB[2];
      pA[0] = *(const ui4*)(pg);
      pA[1] = *(const ui4*)(pg + 1024);
      PSTEP(pA, pB, 0);  PSTEP(pB, pA, 1);  PSTEP(pA, pB, 2);  PSTEP(pB, pA, 3);
      PSTEP(pA, pB, 4);  PSTEP(pB, pA, 5);  PSTEP(pA, pB, 6);  PSTEP(pB, pA, 7);
      PSTEP(pA, pB, 8);  PSTEP(pB, pA, 9);  PSTEP(pA, pB, 10); PSTEP(pB, pA, 11);
      PSTEP(pA, pB, 12); PSTEP(pB, pA, 13); PSTEP(pA, pB, 14); PSTEP(pB, pA, 15);
    }
#undef PSTEP
  } else if (wid == 1) {
    // ------------------------------ loader --------------------------------
    const char* gsrc = (const char*)P + (size_t)b * 2048 + (size_t)lane * 16;
    char* pbase = (char*)&pring[0][0];
    // prologue: groups 0 and 1 (rows 0..31, 64 loads)
#pragma unroll
    for (int r = 0; r < 32; ++r) {
      async16(pbase + r * 2048,        gsrc + (size_t)r * 32768);
      async16(pbase + r * 2048 + 1024, gsrc + (size_t)r * 32768 + 1024);
    }
    WAITV(32);                       // group 0 landed
    RL(&flags[0], 16u);
#pragma unroll 1
    for (int g = 2; g < 128; ++g) {
      const unsigned needc = (unsigned)((g - 1) * 16);
      { int gd = 1 << 22;
        while (gd-- && AQ(&flags[1]) < needc) __builtin_amdgcn_s_sleep(1); }
      const char* gg2 = gsrc + (size_t)g * 16 * 32768;
      char* bb2 = pbase + (g & 1) * 32768;
#pragma unroll
      for (int r2 = 0; r2 < 16; ++r2) {
        async16(bb2 + r2 * 2048,        gg2 + (size_t)r2 * 32768);
        async16(bb2 + r2 * 2048 + 1024, gg2 + (size_t)r2 * 32768 + 1024);
      }
      WAITV(32);                     // group g-1 landed
      RL(&flags[0], (unsigned)(g * 16));
    }
    WAITV(0);                        // group 127 landed
    RL(&flags[0], 2048u);
  } else {
    // ------------------------------ storers -------------------------------
    const int w = wid - 2;
    const char* hrb = (const char*)&hring[0][0] + (size_t)lane * 8;
#pragma unroll 1
    for (int r = w; r < T_STEPS; r += 2) {
      { int gd = 1 << 18;
        while (gd-- && (int)AQ(&flags[1]) <= r) __builtin_amdgcn_s_sleep(1); }
      const int slot = r & 31;
      float* hd = hout + ((size_t)(r + 1) * BATCH + b) * DIM + 4 * lane;
      float* od = out  + ((size_t)r * BATCH + b) * DIM + 4 * lane;
#pragma unroll
      for (int c = 0; c < 4; ++c) {
        uint2 q = *(const uint2*)(hrb + slot * 2048 + c * 512);
        f16x2 qa = __builtin_bit_cast(f16x2, q.x);
        f16x2 qb = __builtin_bit_cast(f16x2, q.y);
        f32x4 hv;
        hv[0] = (float)qa[0]; hv[1] = (float)qa[1];
        hv[2] = (float)qb[0]; hv[3] = (float)qb[1];
        f32x4 ov;
#pragma unroll
        for (int j = 0; j < 4; ++j) {
          const float x = hv[j];
          ov[j] = x * x / (1.0f + __expf(-x));
        }
        *(f32x4*)(hd + c * 256) = hv;
        *(f32x4*)(od + c * 256) = ov;
      }
      RL(&flags[2 + w], (unsigned)(r + 2));
    }
  }
}

// ---------------------------------------------------------------------------
extern "C" void kernel_launch(void* const* d_in, const int* in_sizes, int n_in,
                              void* d_out, int out_size, void* d_ws, size_t ws_size,
                              hipStream_t stream) {
  const float* x  = (const float*)d_in[0];  // [T,B,D]
  const float* h0 = (const float*)d_in[1];  // [B,D]
  const float* W  = (const float*)d_in[2];  // [D,D]
  const float* Wg = (const float*)d_in[3];  // [D,D]
  const float* bb = (const float*)d_in[4];  // [D]
  const float* bg = (const float*)d_in[5];  // [D]

  float* out  = (float*)d_out;                              // [T,B,D]
  float* hout = out + (size_t)T_STEPS * BATCH * DIM;        // [T+1,B,D]

  char* ws = (char*)d_ws;
  f16* xh  = (f16*)(ws);                                    // 64 MiB
  f16* wh  = (f16*)(ws + (size_t)67108864);                 // 2 MiB
  f16* wgh = (f16*)(ws + (size_t)69206016);                 // 2 MiB
  f16* P   = (f16*)(ws + (size_t)71303168);                 // 64 MiB

  cvt_kernel<<<16384, 256, 0, stream>>>(x,  xh,  4194304);
  cvt_kernel<<<512,   256, 0, stream>>>(W,  wh,  131072);
  cvt_kernel<<<512,   256, 0, stream>>>(Wg, wgh, 131072);

  dual_gemm<<<2048, 256, 0, stream>>>(xh, wh, wgh, bb, bg, P);

  scan_pc_kernel<<<BATCH, 256, 0, stream>>>(P, h0, hout, out);
}

// Round 12
// 564.928 us; speedup vs baseline: 1.5497x; 1.5497x over previous
//
#include <hip/hip_runtime.h>
#include <hip/hip_fp16.h>

typedef _Float16 f16;
typedef _Float16 f16x8 __attribute__((ext_vector_type(8)));
typedef float    f32x2 __attribute__((ext_vector_type(2)));
typedef float    f32x4 __attribute__((ext_vector_type(4)));
typedef unsigned ui4   __attribute__((ext_vector_type(4)));

#define T_STEPS 2048
#define BATCH   16
#define DIM     1024

// ---------------------------------------------------------------------------
__device__ __forceinline__ void async16(void* lds, const void* g) {
  __builtin_amdgcn_global_load_lds(
      (const __attribute__((address_space(1))) void*)g,
      (__attribute__((address_space(3))) void*)lds, 16, 0, 0);
}

__device__ __forceinline__ float fma_mix_lo(unsigned p, float one, float h) {
  float d;
  asm("v_fma_mix_f32 %0, %1, %2, %3 op_sel:[0,0,0] op_sel_hi:[1,0,0]"
      : "=v"(d) : "v"(p), "v"(one), "v"(h));
  return d;
}
__device__ __forceinline__ float fma_mix_hi(unsigned p, float one, float h) {
  float d;
  asm("v_fma_mix_f32 %0, %1, %2, %3 op_sel:[1,0,0] op_sel_hi:[1,0,0]"
      : "=v"(d) : "v"(p), "v"(one), "v"(h));
  return d;
}

template <int CTRL>
__device__ __forceinline__ float dpp_add(float x) {
  int m = __builtin_amdgcn_update_dpp(0, __float_as_int(x), CTRL, 0xf, 0xf, true);
  return x + __int_as_float(m);
}

// ---------------------------------------------------------------------------
// f32 -> f16 convert, 8 elems/thread
__global__ void cvt_kernel(const float* __restrict__ src, f16* __restrict__ dst,
                           int n8) {
  int i = blockIdx.x * 256 + threadIdx.x;
  if (i >= n8) return;
  const float4* s4 = reinterpret_cast<const float4*>(src);
  float4 a = s4[2 * i], b = s4[2 * i + 1];
  f16x8 o;
  o[0] = (f16)a.x; o[1] = (f16)a.y; o[2] = (f16)a.z; o[3] = (f16)a.w;
  o[4] = (f16)b.x; o[5] = (f16)b.y; o[6] = (f16)b.z; o[7] = (f16)b.w;
  *reinterpret_cast<f16x8*>(dst + (size_t)i * 8) = o;
}

// ---------------------------------------------------------------------------
// Dual GEMM (R6 proven): P[m,e] = (x@W^T + b) * sigmoid(x@Wg^T + bg)
__global__ __launch_bounds__(256, 2)
void dual_gemm(const f16* __restrict__ xh, const f16* __restrict__ wh,
               const f16* __restrict__ wgh, const float* __restrict__ bias,
               const float* __restrict__ biasg, f16* __restrict__ P) {
  __shared__ f16 As[128 * 32];
  __shared__ f16 Bs[128 * 32];
  __shared__ f16 Gs[128 * 32];

  const int tid = threadIdx.x;
  const int bid = blockIdx.x;
  const int swz = ((bid & 7) << 8) | (bid >> 3);
  const int m0 = (swz >> 3) * 128;
  const int e0 = (swz & 7) * 128;

  const int lane = tid & 63;
  const int wave = tid >> 6;
  const int wrow = (wave >> 1) * 64;
  const int wcol = (wave & 1) * 64;
  const int fr = lane & 15;
  const int fc = lane >> 4;

  f32x4 acc1[4][4], acc2[4][4];
#pragma unroll
  for (int i = 0; i < 4; ++i)
#pragma unroll
    for (int j = 0; j < 4; ++j) {
      acc1[i][j] = {0.f, 0.f, 0.f, 0.f};
      acc2[i][j] = {0.f, 0.f, 0.f, 0.f};
    }

  const int    srow  = tid >> 2;
  const size_t sbyte = (size_t)(tid & 3) * 16;
  const char* ga = (const char*)xh  + ((size_t)(m0 + srow)) * 2048 + sbyte;
  const char* gb = (const char*)wh  + ((size_t)(e0 + srow)) * 2048 + sbyte;
  const char* gg = (const char*)wgh + ((size_t)(e0 + srow)) * 2048 + sbyte;
  char* la = (char*)&As[0] + (size_t)wave * 1024;
  char* lb = (char*)&Bs[0] + (size_t)wave * 1024;
  char* lg = (char*)&Gs[0] + (size_t)wave * 1024;

  for (int kk = 0; kk < 1024; kk += 32) {
    const size_t ko = (size_t)kk * 2;
    async16(la,        ga + ko);
    async16(la + 4096, ga + ko + (size_t)64 * 2048);
    async16(lb,        gb + ko);
    async16(lb + 4096, gb + ko + (size_t)64 * 2048);
    async16(lg,        gg + ko);
    async16(lg + 4096, gg + ko + (size_t)64 * 2048);
    asm volatile("s_waitcnt vmcnt(0)" ::: "memory");
    __syncthreads();

    f16x8 af[4], bf[4], gf[4];
#pragma unroll
    for (int i = 0; i < 4; ++i) {
      af[i] = *reinterpret_cast<const f16x8*>(&As[(wrow + i * 16 + fr) * 32 + fc * 8]);
      bf[i] = *reinterpret_cast<const f16x8*>(&Bs[(wcol + i * 16 + fr) * 32 + fc * 8]);
      gf[i] = *reinterpret_cast<const f16x8*>(&Gs[(wcol + i * 16 + fr) * 32 + fc * 8]);
    }
#pragma unroll
    for (int mi = 0; mi < 4; ++mi)
#pragma unroll
      for (int ni = 0; ni < 4; ++ni) {
        acc1[mi][ni] = __builtin_amdgcn_mfma_f32_16x16x32_f16(af[mi], bf[ni], acc1[mi][ni], 0, 0, 0);
        acc2[mi][ni] = __builtin_amdgcn_mfma_f32_16x16x32_f16(af[mi], gf[ni], acc2[mi][ni], 0, 0, 0);
      }
    __syncthreads();
  }

#pragma unroll
  for (int ni = 0; ni < 4; ++ni) {
    const int e = e0 + wcol + ni * 16 + fr;
    const float bb  = bias[e];
    const float bbg = biasg[e];
#pragma unroll
    for (int mi = 0; mi < 4; ++mi) {
      const int mrow = m0 + wrow + mi * 16 + fc * 4;
#pragma unroll
      for (int j = 0; j < 4; ++j) {
        float z1 = acc1[mi][ni][j] + bb;
        float z2 = acc2[mi][ni][j] + bbg;
        float s  = 1.0f / (1.0f + __expf(-z2));
        P[(size_t)(mrow + j) * DIM + e] = (f16)(z1 * s);
      }
    }
  }
}

// ---------------------------------------------------------------------------
// Sequential scan, one wave per batch row. R6 structure, but the depth-8
// P-prefetch ring lives in inline-asm loads the compiler CANNOT sink
// (R2/R5/R8: C-level rings were repeatedly collapsed to depth ~1-2,
// exposing ~200cy load latency/step — VGPR_Count=56 proved it).
//  - all loop memory ops are volatile asm => exact vmcnt FIFO counts
//    (2 loads + 4 stores per step; steady-state wait = vmcnt(46))
//  - per-step wait is a dataflow-tied "s_waitcnt vmcnt(N)" with "+v"
//    passthrough of the consumed regs: orders consumers AFTER the wait via
//    SSA, no "memory" clobber, no sched_barrier => VALU schedule stays free.
// Element map: lane l owns f32 elems 8l..8l+7 (h4[0],h4[1]) and
// 512+8l..512+8l+7 (h4[2],h4[3]). P row bytes: Q0 @ lane*16, Q1 @ +1024.
__global__ __launch_bounds__(64, 1)
void scan_kernel(const f16* __restrict__ P, const float* __restrict__ h0,
                 float* __restrict__ hout) {
  const int b = blockIdx.x;
  const int lane = threadIdx.x;

  f32x4 h4[4];
  {
    const f32x4* s = (const f32x4*)(h0 + (size_t)b * DIM);
    f32x4* d = (f32x4*)(hout + (size_t)b * DIM);  // h row 0 = h0
    h4[0] = s[2 * lane];       d[2 * lane]       = h4[0];
    h4[1] = s[2 * lane + 1];   d[2 * lane + 1]   = h4[1];
    h4[2] = s[128 + 2 * lane]; d[128 + 2 * lane] = h4[2];
    h4[3] = s[129 + 2 * lane]; d[129 + 2 * lane] = h4[3];
  }
  // Drain the C-level h0 ops so the asm FIFO accounting starts from zero.
  // h4 passthrough: later uses read asm outputs -> compiler adds no waits.
  asm volatile("s_waitcnt vmcnt(0)"
               : "+v"(h4[0]), "+v"(h4[1]), "+v"(h4[2]), "+v"(h4[3])
               :: "memory");

  const char* pld = (const char*)P + (size_t)b * 2048 + (size_t)lane * 16;
  char* hsp = (char*)hout + (size_t)BATCH * DIM * 4  // row 1
            + (size_t)b * DIM * 4 + (size_t)lane * 32;
  const float one = 1.0f;

  ui4 q00, q01, q10, q11, q20, q21, q30, q31;
  ui4 q40, q41, q50, q51, q60, q61, q70, q71;

#define PLOAD(Q0, Q1, R)                                                      \
  { const char* ap_ = pld + (size_t)(R) * 32768;                              \
    asm volatile("global_load_dwordx4 %0, %1, off" : "=v"(Q0) : "v"(ap_));    \
    asm volatile("global_load_dwordx4 %0, %1, off offset:1024"                \
                 : "=v"(Q1) : "v"(ap_)); }

  PLOAD(q00, q01, 0) PLOAD(q10, q11, 1) PLOAD(q20, q21, 2) PLOAD(q30, q31, 3)
  PLOAD(q40, q41, 4) PLOAD(q50, q51, 5) PLOAD(q60, q61, 6) PLOAD(q70, q71, 7)

#define STEP(Q0, Q1, WN, T)                                                   \
  {                                                                           \
    asm volatile("s_waitcnt vmcnt(" WN ")" : "+v"(Q0), "+v"(Q1));             \
    f32x4 v4[4];                                                              \
    v4[0][0] = fma_mix_lo(Q0[0], one, h4[0][0]);                              \
    v4[0][1] = fma_mix_hi(Q0[0], one, h4[0][1]);                              \
    v4[0][2] = fma_mix_lo(Q0[1], one, h4[0][2]);                              \
    v4[0][3] = fma_mix_hi(Q0[1], one, h4[0][3]);                              \
    v4[1][0] = fma_mix_lo(Q0[2], one, h4[1][0]);                              \
    v4[1][1] = fma_mix_hi(Q0[2], one, h4[1][1]);                              \
    v4[1][2] = fma_mix_lo(Q0[3], one, h4[1][2]);                              \
    v4[1][3] = fma_mix_hi(Q0[3], one, h4[1][3]);                              \
    v4[2][0] = fma_mix_lo(Q1[0], one, h4[2][0]);                              \
    v4[2][1] = fma_mix_hi(Q1[0], one, h4[2][1]);                              \
    v4[2][2] = fma_mix_lo(Q1[1], one, h4[2][2]);                              \
    v4[2][3] = fma_mix_hi(Q1[1], one, h4[2][3]);                              \
    v4[3][0] = fma_mix_lo(Q1[2], one, h4[3][0]);                              \
    v4[3][1] = fma_mix_hi(Q1[2], one, h4[3][1]);                              \
    v4[3][2] = fma_mix_lo(Q1[3], one, h4[3][2]);                              \
    v4[3][3] = fma_mix_hi(Q1[3], one, h4[3][3]);                              \
    { /* reissue this slot for row (T)+8 (branch-free wrap) */                \
      const int tw_ = ((T) + 8) & (T_STEPS - 1);                              \
      const char* ap_ = pld + (size_t)tw_ * 32768;                            \
      asm volatile("global_load_dwordx4 %0, %1, off" : "=v"(Q0) : "v"(ap_));  \
      asm volatile("global_load_dwordx4 %0, %1, off offset:1024"              \
                   : "=v"(Q1) : "v"(ap_));                                    \
    }                                                                         \
    f32x2 sE, sO;                                                             \
    {                                                                         \
      f32x2 e0v = __builtin_shufflevector(v4[0], v4[0], 0, 1);                \
      f32x2 o0v = __builtin_shufflevector(v4[0], v4[0], 2, 3);                \
      sE = e0v * e0v;                                                         \
      sO = o0v * o0v;                                                         \
      _Pragma("unroll")                                                       \
      for (int c = 1; c < 4; ++c) {                                           \
        f32x2 ec = __builtin_shufflevector(v4[c], v4[c], 0, 1);               \
        f32x2 oc = __builtin_shufflevector(v4[c], v4[c], 2, 3);               \
        sE += ec * ec;                                                        \
        sO += oc * oc;                                                        \
      }                                                                       \
    }                                                                         \
    f32x2 sC = sE + sO;                                                       \
    float ss = sC[0] + sC[1];                                                 \
    ss = dpp_add<0x111>(ss);                                                  \
    ss = dpp_add<0x112>(ss);                                                  \
    ss = dpp_add<0x114>(ss);                                                  \
    ss = dpp_add<0x118>(ss);                                                  \
    ss = dpp_add<0x142>(ss);                                                  \
    ss = dpp_add<0x143>(ss);                                                  \
    float tot = __int_as_float(__builtin_amdgcn_readlane(__float_as_int(ss), 63)); \
    float rs = __builtin_amdgcn_rsqf(fmaf(tot, 9.765625e-4f, 1e-6f));         \
    _Pragma("unroll")                                                         \
    for (int c = 0; c < 4; ++c) h4[c] = v4[c] * rs;                           \
    asm volatile("global_store_dwordx4 %0, %1, off"                           \
                 :: "v"(hsp), "v"(h4[0]));                                    \
    asm volatile("global_store_dwordx4 %0, %1, off offset:16"                 \
                 :: "v"(hsp), "v"(h4[1]));                                    \
    asm volatile("global_store_dwordx4 %0, %1, off offset:2048"               \
                 :: "v"(hsp), "v"(h4[2]));                                    \
    asm volatile("global_store_dwordx4 %0, %1, off offset:2064"               \
                 :: "v"(hsp), "v"(h4[3]));                                    \
    hsp += (size_t)BATCH * DIM * 4;                                           \
  }

  // peeled steps 0..7: exact prologue counts (prologue = 16 loads, no stores)
  STEP(q00, q01, "14", 0)
  STEP(q10, q11, "18", 1)
  STEP(q20, q21, "22", 2)
  STEP(q30, q31, "26", 3)
  STEP(q40, q41, "30", 4)
  STEP(q50, q51, "34", 5)
  STEP(q60, q61, "38", 6)
  STEP(q70, q71, "42", 7)

  // steady state: slot loads issued 8 steps ago; newer FIFO entries =
  // 4 stores (that step) + 7 * (2L + 4S) = 46.
#pragma unroll 1
  for (int t0 = 8; t0 < T_STEPS; t0 += 8) {
    STEP(q00, q01, "46", t0 + 0)
    STEP(q10, q11, "46", t0 + 1)
    STEP(q20, q21, "46", t0 + 2)
    STEP(q30, q31, "46", t0 + 3)
    STEP(q40, q41, "46", t0 + 4)
    STEP(q50, q51, "46", t0 + 5)
    STEP(q60, q61, "46", t0 + 6)
    STEP(q70, q71, "46", t0 + 7)
  }
#undef STEP
#undef PLOAD
}

// ---------------------------------------------------------------------------
// out = h * silu(h) = h^2 * sigmoid(h), elementwise over hs (h rows 1..T)
__global__ void silu_out_kernel(const float* __restrict__ hsrc,
                                float* __restrict__ out, int n4) {
  int stride = gridDim.x * blockDim.x;
  for (int i = blockIdx.x * blockDim.x + threadIdx.x; i < n4; i += stride) {
    float4 v = reinterpret_cast<const float4*>(hsrc)[i];
    float4 o;
    o.x = v.x * v.x / (1.0f + __expf(-v.x));
    o.y = v.y * v.y / (1.0f + __expf(-v.y));
    o.z = v.z * v.z / (1.0f + __expf(-v.z));
    o.w = v.w * v.w / (1.0f + __expf(-v.w));
    reinterpret_cast<float4*>(out)[i] = o;
  }
}

// ---------------------------------------------------------------------------
extern "C" void kernel_launch(void* const* d_in, const int* in_sizes, int n_in,
                              void* d_out, int out_size, void* d_ws, size_t ws_size,
                              hipStream_t stream) {
  const float* x  = (const float*)d_in[0];  // [T,B,D]
  const float* h0 = (const float*)d_in[1];  // [B,D]
  const float* W  = (const float*)d_in[2];  // [D,D]
  const float* Wg = (const float*)d_in[3];  // [D,D]
  const float* bb = (const float*)d_in[4];  // [D]
  const float* bg = (const float*)d_in[5];  // [D]

  float* out  = (float*)d_out;                              // [T,B,D]
  float* hout = out + (size_t)T_STEPS * BATCH * DIM;        // [T+1,B,D]

  char* ws = (char*)d_ws;
  f16* xh  = (f16*)(ws);                                    // 64 MiB
  f16* wh  = (f16*)(ws + (size_t)67108864);                 // 2 MiB
  f16* wgh = (f16*)(ws + (size_t)69206016);                 // 2 MiB
  f16* P   = (f16*)(ws + (size_t)71303168);                 // 64 MiB

  cvt_kernel<<<16384, 256, 0, stream>>>(x,  xh,  4194304);
  cvt_kernel<<<512,   256, 0, stream>>>(W,  wh,  131072);
  cvt_kernel<<<512,   256, 0, stream>>>(Wg, wgh, 131072);

  dual_gemm<<<2048, 256, 0, stream>>>(xh, wh, wgh, bb, bg, P);

  scan_kernel<<<BATCH, 64, 0, stream>>>(P, h0, hout);

  silu_out_kernel<<<2048, 256, 0, stream>>>(hout + BATCH * DIM, out, 8388608);
}

// Round 15
// 564.408 us; speedup vs baseline: 1.5511x; 1.0009x over previous
//
#include <hip/hip_runtime.h>
#include <hip/hip_fp16.h>

typedef _Float16 f16;
typedef _Float16 f16x8 __attribute__((ext_vector_type(8)));
typedef float    f32x2 __attribute__((ext_vector_type(2)));
typedef float    f32x4 __attribute__((ext_vector_type(4)));
typedef unsigned ui4   __attribute__((ext_vector_type(4)));

#define T_STEPS 2048
#define BATCH   16
#define DIM     1024

// ---------------------------------------------------------------------------
__device__ __forceinline__ void async16(void* lds, const void* g) {
  __builtin_amdgcn_global_load_lds(
      (const __attribute__((address_space(1))) void*)g,
      (__attribute__((address_space(3))) void*)lds, 16, 0, 0);
}

// v = f16 (low/high half of packed u32) * 1.0 + h  (proven R5-R12 form:
// f16 operand in src0, op_sel_hi:[1,0,0])
__device__ __forceinline__ float fma_mix_lo(unsigned p, float one, float h) {
  float d;
  asm("v_fma_mix_f32 %0, %1, %2, %3 op_sel:[0,0,0] op_sel_hi:[1,0,0]"
      : "=v"(d) : "v"(p), "v"(one), "v"(h));
  return d;
}
__device__ __forceinline__ float fma_mix_hi(unsigned p, float one, float h) {
  float d;
  asm("v_fma_mix_f32 %0, %1, %2, %3 op_sel:[1,0,0] op_sel_hi:[1,0,0]"
      : "=v"(d) : "v"(p), "v"(one), "v"(h));
  return d;
}

// proven DPP reduce element (R4-R12): builtin path, compiler handles hazards
template <int CTRL>
__device__ __forceinline__ float dpp_add(float x) {
  int m = __builtin_amdgcn_update_dpp(0, __float_as_int(x), CTRL, 0xf, 0xf, true);
  return x + __int_as_float(m);
}

// ---------------------------------------------------------------------------
// f32 -> f16 convert, 8 elems/thread
__global__ void cvt_kernel(const float* __restrict__ src, f16* __restrict__ dst,
                           int n8) {
  int i = blockIdx.x * 256 + threadIdx.x;
  if (i >= n8) return;
  const float4* s4 = reinterpret_cast<const float4*>(src);
  float4 a = s4[2 * i], b = s4[2 * i + 1];
  f16x8 o;
  o[0] = (f16)a.x; o[1] = (f16)a.y; o[2] = (f16)a.z; o[3] = (f16)a.w;
  o[4] = (f16)b.x; o[5] = (f16)b.y; o[6] = (f16)b.z; o[7] = (f16)b.w;
  *reinterpret_cast<f16x8*>(dst + (size_t)i * 8) = o;
}

// merged weight convert: blocks 0..511 -> W, 512..1023 -> Wg (131072 x8 each)
__global__ void cvt_w_kernel(const float* __restrict__ W,
                             const float* __restrict__ Wg,
                             f16* __restrict__ wh, f16* __restrict__ wgh) {
  int gi = blockIdx.x * 256 + threadIdx.x;
  const float* src = (gi < 131072) ? W : Wg;
  f16* dst = (gi < 131072) ? wh : wgh;
  int i = gi & 131071;
  const float4* s4 = reinterpret_cast<const float4*>(src);
  float4 a = s4[2 * i], b = s4[2 * i + 1];
  f16x8 o;
  o[0] = (f16)a.x; o[1] = (f16)a.y; o[2] = (f16)a.z; o[3] = (f16)a.w;
  o[4] = (f16)b.x; o[5] = (f16)b.y; o[6] = (f16)b.z; o[7] = (f16)b.w;
  *reinterpret_cast<f16x8*>(dst + (size_t)i * 8) = o;
}

// ---------------------------------------------------------------------------
// Dual GEMM, BK=64: two 32-wide K-subtiles staged per iteration into As[2]
// (second subtile = global byte offset +64), 64 MFMAs per barrier pair ->
// 16 iterations, HALF the vmcnt(0)+barrier drains of the BK=32 version.
// P[m,e] = (x@W^T + b) * sigmoid(x@Wg^T + bg), f16 out.
__global__ __launch_bounds__(256, 2)
void dual_gemm(const f16* __restrict__ xh, const f16* __restrict__ wh,
               const f16* __restrict__ wgh, const float* __restrict__ bias,
               const float* __restrict__ biasg, f16* __restrict__ P) {
  __shared__ f16 As[2][128 * 32];   // 16 KB: subtile h at f16 offset h*4096
  __shared__ f16 Bs[2][128 * 32];
  __shared__ f16 Gs[2][128 * 32];

  const int tid = threadIdx.x;
  const int bid = blockIdx.x;
  const int swz = ((bid & 7) << 8) | (bid >> 3);
  const int m0 = (swz >> 3) * 128;
  const int e0 = (swz & 7) * 128;

  const int lane = tid & 63;
  const int wave = tid >> 6;
  const int wrow = (wave >> 1) * 64;
  const int wcol = (wave & 1) * 64;
  const int fr = lane & 15;
  const int fc = lane >> 4;

  f32x4 acc1[4][4], acc2[4][4];
#pragma unroll
  for (int i = 0; i < 4; ++i)
#pragma unroll
    for (int j = 0; j < 4; ++j) {
      acc1[i][j] = {0.f, 0.f, 0.f, 0.f};
      acc2[i][j] = {0.f, 0.f, 0.f, 0.f};
    }

  // staging map (same per-thread map as BK=32 version):
  // row = srow (+64 for second 4KB call), col byte = sbyte (+64 for subtile 1)
  const int    srow  = tid >> 2;                 // 0..63
  const size_t sbyte = (size_t)(tid & 3) * 16;   // 0..48
  const char* ga = (const char*)xh  + ((size_t)(m0 + srow)) * 2048 + sbyte;
  const char* gb = (const char*)wh  + ((size_t)(e0 + srow)) * 2048 + sbyte;
  const char* gg = (const char*)wgh + ((size_t)(e0 + srow)) * 2048 + sbyte;
  char* la = (char*)&As[0][0] + (size_t)wave * 1024;
  char* lb = (char*)&Bs[0][0] + (size_t)wave * 1024;
  char* lg = (char*)&Gs[0][0] + (size_t)wave * 1024;

  for (int kk = 0; kk < 1024; kk += 64) {
    const size_t ko = (size_t)kk * 2;  // bytes along K
    // subtile 0 (K cols kk..kk+31)
    async16(la,        ga + ko);
    async16(la + 4096, ga + ko + (size_t)64 * 2048);
    async16(lb,        gb + ko);
    async16(lb + 4096, gb + ko + (size_t)64 * 2048);
    async16(lg,        gg + ko);
    async16(lg + 4096, gg + ko + (size_t)64 * 2048);
    // subtile 1 (K cols kk+32..kk+63): global +64 bytes, LDS +8192
    async16(la + 8192,        ga + ko + 64);
    async16(la + 8192 + 4096, ga + ko + 64 + (size_t)64 * 2048);
    async16(lb + 8192,        gb + ko + 64);
    async16(lb + 8192 + 4096, gb + ko + 64 + (size_t)64 * 2048);
    async16(lg + 8192,        gg + ko + 64);
    async16(lg + 8192 + 4096, gg + ko + 64 + (size_t)64 * 2048);
    asm volatile("s_waitcnt vmcnt(0)" ::: "memory");
    __syncthreads();

#pragma unroll
    for (int h = 0; h < 2; ++h) {
      f16x8 af[4], bf[4], gf[4];
#pragma unroll
      for (int i = 0; i < 4; ++i) {
        af[i] = *reinterpret_cast<const f16x8*>(&As[h][(wrow + i * 16 + fr) * 32 + fc * 8]);
        bf[i] = *reinterpret_cast<const f16x8*>(&Bs[h][(wcol + i * 16 + fr) * 32 + fc * 8]);
        gf[i] = *reinterpret_cast<const f16x8*>(&Gs[h][(wcol + i * 16 + fr) * 32 + fc * 8]);
      }
#pragma unroll
      for (int mi = 0; mi < 4; ++mi)
#pragma unroll
        for (int ni = 0; ni < 4; ++ni) {
          acc1[mi][ni] = __builtin_amdgcn_mfma_f32_16x16x32_f16(af[mi], bf[ni], acc1[mi][ni], 0, 0, 0);
          acc2[mi][ni] = __builtin_amdgcn_mfma_f32_16x16x32_f16(af[mi], gf[ni], acc2[mi][ni], 0, 0, 0);
        }
    }
    __syncthreads();
  }

#pragma unroll
  for (int ni = 0; ni < 4; ++ni) {
    const int e = e0 + wcol + ni * 16 + fr;
    const float bb  = bias[e];
    const float bbg = biasg[e];
#pragma unroll
    for (int mi = 0; mi < 4; ++mi) {
      const int mrow = m0 + wrow + mi * 16 + fc * 4;
#pragma unroll
      for (int j = 0; j < 4; ++j) {
        float z1 = acc1[mi][ni][j] + bb;
        float z2 = acc2[mi][ni][j] + bbg;
        float s  = 1.0f / (1.0f + __expf(-z2));
        P[(size_t)(mrow + j) * DIM + e] = (f16)(z1 * s);
      }
    }
  }
}

// ---------------------------------------------------------------------------
// Sequential scan — R12 PROVEN skeleton (asm ring, exact counted vmcnt,
// builtin DPP) with one safe change: tree-shaped square-accumulate
// (reassociation only; chain depth 4 -> 2 on the packed partials).
__global__ __launch_bounds__(64, 1)
void scan_kernel(const f16* __restrict__ P, const float* __restrict__ h0,
                 float* __restrict__ hout) {
  const int b = blockIdx.x;
  const int lane = threadIdx.x;

  f32x4 h4[4];
  {
    const f32x4* s = (const f32x4*)(h0 + (size_t)b * DIM);
    f32x4* d = (f32x4*)(hout + (size_t)b * DIM);  // h row 0 = h0
    h4[0] = s[2 * lane];       d[2 * lane]       = h4[0];
    h4[1] = s[2 * lane + 1];   d[2 * lane + 1]   = h4[1];
    h4[2] = s[128 + 2 * lane]; d[128 + 2 * lane] = h4[2];
    h4[3] = s[129 + 2 * lane]; d[129 + 2 * lane] = h4[3];
  }
  asm volatile("s_waitcnt vmcnt(0)"
               : "+v"(h4[0]), "+v"(h4[1]), "+v"(h4[2]), "+v"(h4[3])
               :: "memory");

  const char* pld = (const char*)P + (size_t)b * 2048 + (size_t)lane * 16;
  char* hsp = (char*)hout + (size_t)BATCH * DIM * 4  // row 1
            + (size_t)b * DIM * 4 + (size_t)lane * 32;
  const float one = 1.0f;

  ui4 q00, q01, q10, q11, q20, q21, q30, q31;
  ui4 q40, q41, q50, q51, q60, q61, q70, q71;

#define PLOAD(Q0, Q1, R)                                                      \
  { const char* ap_ = pld + (size_t)(R) * 32768;                              \
    asm volatile("global_load_dwordx4 %0, %1, off" : "=v"(Q0) : "v"(ap_));    \
    asm volatile("global_load_dwordx4 %0, %1, off offset:1024"                \
                 : "=v"(Q1) : "v"(ap_)); }

  PLOAD(q00, q01, 0) PLOAD(q10, q11, 1) PLOAD(q20, q21, 2) PLOAD(q30, q31, 3)
  PLOAD(q40, q41, 4) PLOAD(q50, q51, 5) PLOAD(q60, q61, 6) PLOAD(q70, q71, 7)

#define STEP(Q0, Q1, WN, T)                                                   \
  {                                                                           \
    asm volatile("s_waitcnt vmcnt(" WN ")" : "+v"(Q0), "+v"(Q1));             \
    f32x4 v4[4];                                                              \
    v4[0][0] = fma_mix_lo(Q0[0], one, h4[0][0]);                              \
    v4[0][1] = fma_mix_hi(Q0[0], one, h4[0][1]);                              \
    v4[0][2] = fma_mix_lo(Q0[1], one, h4[0][2]);                              \
    v4[0][3] = fma_mix_hi(Q0[1], one, h4[0][3]);                              \
    v4[1][0] = fma_mix_lo(Q0[2], one, h4[1][0]);                              \
    v4[1][1] = fma_mix_hi(Q0[2], one, h4[1][1]);                              \
    v4[1][2] = fma_mix_lo(Q0[3], one, h4[1][2]);                              \
    v4[1][3] = fma_mix_hi(Q0[3], one, h4[1][3]);                              \
    v4[2][0] = fma_mix_lo(Q1[0], one, h4[2][0]);                              \
    v4[2][1] = fma_mix_hi(Q1[0], one, h4[2][1]);                              \
    v4[2][2] = fma_mix_lo(Q1[1], one, h4[2][2]);                              \
    v4[2][3] = fma_mix_hi(Q1[1], one, h4[2][3]);                              \
    v4[3][0] = fma_mix_lo(Q1[2], one, h4[3][0]);                              \
    v4[3][1] = fma_mix_hi(Q1[2], one, h4[3][1]);                              \
    v4[3][2] = fma_mix_lo(Q1[3], one, h4[3][2]);                              \
    v4[3][3] = fma_mix_hi(Q1[3], one, h4[3][3]);                              \
    { /* reissue this slot for row (T)+8 (branch-free wrap) */                \
      const int tw_ = ((T) + 8) & (T_STEPS - 1);                              \
      const char* ap_ = pld + (size_t)tw_ * 32768;                            \
      asm volatile("global_load_dwordx4 %0, %1, off" : "=v"(Q0) : "v"(ap_));  \
      asm volatile("global_load_dwordx4 %0, %1, off offset:1024"              \
                   : "=v"(Q1) : "v"(ap_));                                    \
    }                                                                         \
    /* tree square-accumulate (reassociated, depth 2 on packed partials) */   \
    f32x2 m0, m1, m2, m3;                                                     \
    {                                                                         \
      f32x2 e_, o_;                                                           \
      e_ = __builtin_shufflevector(v4[0], v4[0], 0, 1);                       \
      o_ = __builtin_shufflevector(v4[0], v4[0], 2, 3);                       \
      m0 = e_ * e_; m0 += o_ * o_;                                            \
      e_ = __builtin_shufflevector(v4[1], v4[1], 0, 1);                       \
      o_ = __builtin_shufflevector(v4[1], v4[1], 2, 3);                       \
      m1 = e_ * e_; m1 += o_ * o_;                                            \
      e_ = __builtin_shufflevector(v4[2], v4[2], 0, 1);                       \
      o_ = __builtin_shufflevector(v4[2], v4[2], 2, 3);                       \
      m2 = e_ * e_; m2 += o_ * o_;                                            \
      e_ = __builtin_shufflevector(v4[3], v4[3], 0, 1);                       \
      o_ = __builtin_shufflevector(v4[3], v4[3], 2, 3);                       \
      m3 = e_ * e_; m3 += o_ * o_;                                            \
    }                                                                         \
    f32x2 s01 = m0 + m1, s23 = m2 + m3;                                       \
    f32x2 sC = s01 + s23;                                                     \
    float ss = sC[0] + sC[1];                                                 \
    ss = dpp_add<0x111>(ss);                                                  \
    ss = dpp_add<0x112>(ss);                                                  \
    ss = dpp_add<0x114>(ss);                                                  \
    ss = dpp_add<0x118>(ss);                                                  \
    ss = dpp_add<0x142>(ss);                                                  \
    ss = dpp_add<0x143>(ss);                                                  \
    float tot = __int_as_float(__builtin_amdgcn_readlane(__float_as_int(ss), 63)); \
    float rs = __builtin_amdgcn_rsqf(fmaf(tot, 9.765625e-4f, 1e-6f));         \
    _Pragma("unroll")                                                         \
    for (int c = 0; c < 4; ++c) h4[c] = v4[c] * rs;                           \
    asm volatile("global_store_dwordx4 %0, %1, off"                           \
                 :: "v"(hsp), "v"(h4[0]));                                    \
    asm volatile("global_store_dwordx4 %0, %1, off offset:16"                 \
                 :: "v"(hsp), "v"(h4[1]));                                    \
    asm volatile("global_store_dwordx4 %0, %1, off offset:2048"               \
                 :: "v"(hsp), "v"(h4[2]));                                    \
    asm volatile("global_store_dwordx4 %0, %1, off offset:2064"               \
                 :: "v"(hsp), "v"(h4[3]));                                    \
    hsp += (size_t)BATCH * DIM * 4;                                           \
  }

  // peeled steps 0..7: prologue = 16 loads, no stores -> WN = 14 + 4k
  STEP(q00, q01, "14", 0)
  STEP(q10, q11, "18", 1)
  STEP(q20, q21, "22", 2)
  STEP(q30, q31, "26", 3)
  STEP(q40, q41, "30", 4)
  STEP(q50, q51, "34", 5)
  STEP(q60, q61, "38", 6)
  STEP(q70, q71, "42", 7)

  // steady: slot loads issued 8 steps ago; newer FIFO entries =
  // 4 stores (that step) + 7 * (2L + 4S) = 46.
#pragma unroll 1
  for (int t0 = 8; t0 < T_STEPS; t0 += 8) {
    STEP(q00, q01, "46", t0 + 0)
    STEP(q10, q11, "46", t0 + 1)
    STEP(q20, q21, "46", t0 + 2)
    STEP(q30, q31, "46", t0 + 3)
    STEP(q40, q41, "46", t0 + 4)
    STEP(q50, q51, "46", t0 + 5)
    STEP(q60, q61, "46", t0 + 6)
    STEP(q70, q71, "46", t0 + 7)
  }
#undef STEP
#undef PLOAD
}

// ---------------------------------------------------------------------------
// out = h * silu(h) = h^2 * sigmoid(h), elementwise over hs (h rows 1..T)
__global__ void silu_out_kernel(const float* __restrict__ hsrc,
                                float* __restrict__ out, int n4) {
  int stride = gridDim.x * blockDim.x;
  for (int i = blockIdx.x * blockDim.x + threadIdx.x; i < n4; i += stride) {
    float4 v = reinterpret_cast<const float4*>(hsrc)[i];
    float4 o;
    o.x = v.x * v.x / (1.0f + __expf(-v.x));
    o.y = v.y * v.y / (1.0f + __expf(-v.y));
    o.z = v.z * v.z / (1.0f + __expf(-v.z));
    o.w = v.w * v.w / (1.0f + __expf(-v.w));
    reinterpret_cast<float4*>(out)[i] = o;
  }
}

// ---------------------------------------------------------------------------
extern "C" void kernel_launch(void* const* d_in, const int* in_sizes, int n_in,
                              void* d_out, int out_size, void* d_ws, size_t ws_size,
                              hipStream_t stream) {
  const float* x  = (const float*)d_in[0];  // [T,B,D]
  const float* h0 = (const float*)d_in[1];  // [B,D]
  const float* W  = (const float*)d_in[2];  // [D,D]
  const float* Wg = (const float*)d_in[3];  // [D,D]
  const float* bb = (const float*)d_in[4];  // [D]
  const float* bg = (const float*)d_in[5];  // [D]

  float* out  = (float*)d_out;                              // [T,B,D]
  float* hout = out + (size_t)T_STEPS * BATCH * DIM;        // [T+1,B,D]

  char* ws = (char*)d_ws;
  f16* xh  = (f16*)(ws);                                    // 64 MiB
  f16* wh  = (f16*)(ws + (size_t)67108864);                 // 2 MiB
  f16* wgh = (f16*)(ws + (size_t)69206016);                 // 2 MiB
  f16* P   = (f16*)(ws + (size_t)71303168);                 // 64 MiB

  cvt_kernel<<<16384, 256, 0, stream>>>(x, xh, 4194304);
  cvt_w_kernel<<<1024, 256, 0, stream>>>(W, Wg, wh, wgh);

  dual_gemm<<<2048, 256, 0, stream>>>(xh, wh, wgh, bb, bg, P);

  scan_kernel<<<BATCH, 64, 0, stream>>>(P, h0, hout);

  silu_out_kernel<<<2048, 256, 0, stream>>>(hout + BATCH * DIM, out, 8388608);
}